// Round 1
// baseline (246.084 us; speedup 1.0000x reference)
//
#include <hip/hip_runtime.h>

// SegmentationAugmentation: fused affine-grid + trilinear grid_sample (border,
// align_corners=False) for input (float out) and label (bool-as-float out).
//
// R4: R3 was VALU-issue-bound (VALUBusy 70%, HBM at 48% of achievable,
// FETCH_SIZE already ideal). Three VALU cuts, all bit-exact:
//  1) Interleave in/lab as (in,lab) float2 pairs in LDS: 16 ds_read_b32 ->
//     8 ds_read_b64 (one base reg + imm offsets), and the contract(off)
//     accumulate (16 mul + 16 add) becomes 8 packed mul + 8 packed add on
//     <2 x float> (v_pk_mul_f32/v_pk_add_f32; element-wise IEEE, bit-exact).
//     Staging becomes reg-staged (global_load_dwordx4 -> interleaved LDS
//     stores) since global_load_lds can't interleave two buffers.
//  2) Drop the z-edge select path (zb=min(iz0,126), hi, 8 cndmask): read the
//     pair at iz0 and the pair at iz0+1 directly. At iz0==127, fz==+0 so the
//     z1-plane weights are +0 and the one-past value contributes +-0, which
//     is numerically identical to the reference's +0*s[127] (acc cannot be
//     -0 there: at least one z0-plane weight is strictly positive; and -0
//     vs +0 is equal under both absmax and the >0.5 comparator). Rows 0-2
//     read the next row's z=0 (finite data); row 3 reads a 2-dword guard
//     zeroed before the barrier (must not be NaN: NaN*0 = NaN).
//  3) Weight products computed once (scalar), splat into the packed FMA
//     stream.
//
// CORRECTNESS-CRITICAL: label output is a hard comparator (acc > 0.5) with
// voxels ~0.5 ulp from the boundary; all float math must stay bit-exact vs
// numpy: contract(off), strict reference op order, w = (wz*wy)*wx, reference
// corner accumulation order (z outer, y mid, x inner). The LDS relayout only
// changes where values are read from, not their bits.

#define NV 128
#define TOTAL (8 * NV * NV * NV)

typedef float v2f __attribute__((ext_vector_type(2)));

__global__ __launch_bounds__(128) void seg_aug_kernel(
    const float* __restrict__ in,
    const float* __restrict__ lab,
    const float* __restrict__ T,   // 16 floats, 4x4 row-major; rows 0..2 used
    float* __restrict__ out_in,
    float* __restrict__ out_lab)
{
#pragma clang fp contract(off)
    // s2[row][z] = (in, lab) pair; row = {x0y0, x0y1, x1y0, x1y1}.
    // +2 guard dwords (zeroed) so row 3's z=127 "z+1" pair read is finite.
    __shared__ __align__(16) float s[4 * NV * 2 + 2];

    const int t  = threadIdx.x;              // 0..127 = o4 (innermost output dim)
    const int o3 = blockIdx.x & (NV - 1);
    const int o2 = (blockIdx.x >> 7) & (NV - 1);
    const int b  = blockIdx.x >> 14;

    // ---- block-uniform x/y path (computed redundantly per thread) ----
    float p2 = (2.0f * (float)o2 + 1.0f) / 128.0f - 1.0f;
    float p3 = (2.0f * (float)o3 + 1.0f) / 128.0f - 1.0f;
    float ux = (T[0] * p2 + T[1] * p3) + T[3];
    float uy = (T[4] * p2 + T[5] * p3) + T[7];
    float gx = ((ux + 1.0f) * 128.0f - 1.0f) * 0.5f;
    float gy = ((uy + 1.0f) * 128.0f - 1.0f) * 0.5f;
    gx = fminf(fmaxf(gx, 0.0f), 127.0f);
    gy = fminf(fmaxf(gy, 0.0f), 127.0f);
    float fx0f = floorf(gx), fy0f = floorf(gy);
    float fx = gx - fx0f;
    float fy = gy - fy0f;
    const int ix0 = __builtin_amdgcn_readfirstlane((int)fx0f);
    const int iy0 = __builtin_amdgcn_readfirstlane((int)fy0f);
    const int ix1 = min(ix0 + 1, NV - 1);
    const int iy1 = min(iy0 + 1, NV - 1);
    float wx0 = 1.0f - fx, wx1 = fx;
    float wy0 = 1.0f - fy, wy1 = fy;

    // ---- reg-stage the 8 source rows (issue loads early) ----
    // thread t loads the float4 at seg=(t&31) of row rid=(t>>5);
    // rid bit1 -> x1, bit0 -> y1 (matches LDS row order x0y0,x0y1,x1y0,x1y1).
    const size_t bbase = (size_t)b << 21;    // b * 128^3
    const int rid = t >> 5;                  // 0..3
    const int seg = t & 31;
    const int ixS = (rid & 2) ? ix1 : ix0;
    const int iyS = (rid & 1) ? iy1 : iy0;
    const int goff = (ixS * NV + iyS) * NV + seg * 4;
    const float4 i4 = *(const float4*)(in  + bbase + goff);
    const float4 l4 = *(const float4*)(lab + bbase + goff);

    // ---- per-thread z path (overlaps with load latency) ----
    float p4 = (2.0f * (float)t + 1.0f) / 128.0f - 1.0f;
    float uz = T[10] * p4 + T[11];
    float gz = ((uz + 1.0f) * 128.0f - 1.0f) * 0.5f;
    gz = fminf(fmaxf(gz, 0.0f), 127.0f);
    float fz0f = floorf(gz);
    float fz = gz - fz0f;
    const int iz0 = (int)fz0f;               // 0..127
    float wz0 = 1.0f - fz, wz1 = fz;

    if (t < 2) s[4 * NV * 2 + t] = 0.0f;     // finite guard for row3 z=128 read

    // interleave into LDS: dwords (rid*128 + z)*2 + {0:in, 1:lab}
    {
        float* d = &s[(rid * NV + seg * 4) * 2];   // 32B-aligned
        ((float4*)d)[0] = make_float4(i4.x, l4.x, i4.y, l4.y);
        ((float4*)d)[1] = make_float4(i4.z, l4.z, i4.w, l4.w);
    }
    __syncthreads();

    // 8x ds_read_b64: base = iz0*8 bytes, imm offsets row*1024 {+8}
    const v2f* srow = (const v2f*)s;
    v2f a0 = srow[0 * NV + iz0], b0 = srow[0 * NV + iz0 + 1];  // (x0,y0) z0/z1
    v2f a1 = srow[1 * NV + iz0], b1 = srow[1 * NV + iz0 + 1];  // (x0,y1)
    v2f a2 = srow[2 * NV + iz0], b2 = srow[2 * NV + iz0 + 1];  // (x1,y0)
    v2f a3 = srow[3 * NV + iz0], b3 = srow[3 * NV + iz0 + 1];  // (x1,y1)

    // weights, reference order: w = (wz*wy)*wx
    float tz0y0 = wz0 * wy0, tz0y1 = wz0 * wy1;
    float tz1y0 = wz1 * wy0, tz1y1 = wz1 * wy1;
    float w1 = tz0y0 * wx0, w2 = tz0y0 * wx1;
    float w3 = tz0y1 * wx0, w4 = tz0y1 * wx1;
    float w5 = tz1y0 * wx0, w6 = tz1y0 * wx1;
    float w7 = tz1y1 * wx0, w8 = tz1y1 * wx1;

    // reference accumulation order: z outer, y mid, x inner.
    // packed (in,lab): element-wise mul/add, contract(off) => bit-exact.
    v2f acc = {0.0f, 0.0f};
    acc = acc + a0 * w1;
    acc = acc + a2 * w2;
    acc = acc + a1 * w3;
    acc = acc + a3 * w4;
    acc = acc + b0 * w5;
    acc = acc + b2 * w6;
    acc = acc + b1 * w7;
    acc = acc + b3 * w8;

    const int oidx = blockIdx.x * NV + t;    // (b,o2,o3,o4) flat
    out_in[oidx]  = acc.x;
    out_lab[oidx] = (acc.y > 0.5f) ? 1.0f : 0.0f;
}

extern "C" void kernel_launch(void* const* d_in, const int* in_sizes, int n_in,
                              void* d_out, int out_size, void* d_ws, size_t ws_size,
                              hipStream_t stream) {
    const float* in  = (const float*)d_in[0];
    const float* lab = (const float*)d_in[1];
    const float* T   = (const float*)d_in[2];
    float* out_in  = (float*)d_out;
    float* out_lab = (float*)d_out + TOTAL;

    dim3 grid(TOTAL / 128);
    dim3 block(128);
    seg_aug_kernel<<<grid, block, 0, stream>>>(in, lab, T, out_in, out_lab);
}